// Round 1
// 427.445 us; speedup vs baseline: 1.0443x; 1.0443x over previous
//
#include <hip/hip_runtime.h>
#include <hip/hip_bf16.h>
#include <cstdint>
#include <cstddef>

// Problem constants
#define B_SZ 4096
#define T_SZ 4
#define C_SZ 1024
#define H_SZ 8
#define DH_SZ 128
#define NQKV 3072                      // 3*C
#define SCALE_F 0.08838834764831845f   // 128^-0.5

typedef float f32x4 __attribute__((ext_vector_type(4)));
typedef short s16x8 __attribute__((ext_vector_type(8)));

static __device__ __forceinline__ float bf2f(unsigned short u) {
    union { unsigned int i; float f; } x; x.i = ((unsigned int)u) << 16; return x.f;
}
static __device__ __forceinline__ unsigned short f2bf(float f) {
    union { unsigned int i; float f; } x; x.f = f;
    unsigned int r = x.i + 0x7FFFu + ((x.i >> 16) & 1u);   // RNE
    return (unsigned short)(r >> 16);
}

// async global->LDS, 16B per lane; lds base must be wave-uniform (HW adds lane*16)
typedef const __attribute__((address_space(1))) void* gas_ptr;
typedef __attribute__((address_space(3))) void* las_ptr;
static __device__ __forceinline__ void async16(const void* g, void* l) {
    __builtin_amdgcn_global_load_lds((gas_ptr)g, (las_ptr)l, 16, 0, 0);
}

// ---------------- elementwise fp32 -> bf16 ----------------
__global__ __launch_bounds__(256) void cvt_f32_bf16(const float* __restrict__ src,
                                                    unsigned short* __restrict__ dst, int n4) {
    int i = blockIdx.x * 256 + threadIdx.x;
    if (i >= n4) return;
    float4 v = reinterpret_cast<const float4*>(src)[i];
    ushort4 o;
    o.x = f2bf(v.x); o.y = f2bf(v.y); o.z = f2bf(v.z); o.w = f2bf(v.w);
    reinterpret_cast<ushort4*>(dst)[i] = o;
}

// ---------------- transpose + convert: src[K][N] fp32 -> dst[N][K] bf16 (per z=task) --------
__global__ __launch_bounds__(256) void transpose_cvt(const float* __restrict__ src,
                                                     unsigned short* __restrict__ dst,
                                                     int K, int N) {
    __shared__ float tile[32][33];
    const float* s = src + (size_t)blockIdx.z * K * N;
    unsigned short* d = dst + (size_t)blockIdx.z * K * N;
    int n0 = blockIdx.x * 32, k0 = blockIdx.y * 32;
    int tx = threadIdx.x, ty = threadIdx.y;
#pragma unroll
    for (int i = 0; i < 4; i++) {
        int k = k0 + ty + i * 8;
        tile[ty + i * 8][tx] = s[(size_t)k * N + n0 + tx];
    }
    __syncthreads();
#pragma unroll
    for (int i = 0; i < 4; i++) {
        int n = n0 + ty + i * 8;
        d[(size_t)n * K + k0 + tx] = f2bf(tile[tx][ty + i * 8]);
    }
}

// ---------------- 256x256 8-phase bf16 MFMA GEMM (T2+T3+T4+T5 stack) ----------------
// A: bf16, row m of task t at A + t*C + m*(T*C), K = C = 1024
// Bt: bf16 [T][NSIZE][K] (B transposed), bias: fp32 [T][NSIZE]
// EPI 0: out_bf[(m*T+t)*NSIZE + n] = bf16(acc + bias)
// EPI 1: out_f [(m*T+t)*NSIZE + n] = acc + bias + resid[...]
//
// Structure (per guide §5 template, m194-m201 / m248):
//   BM=BN=256, BK=64, 8 waves (2M x 4N), 512 thr, LDS 128 KiB = 2buf x {A 32KB, B 32KB}.
//   Each buf half-tile = 128 rows x 64 cols bf16 = 16 KiB = 2 global_load_lds_dwordx4/thread.
//   LDS chunk swizzle: stored_chunk = data_chunk ^ (row&7)  (16B chunks, 8/row)
//     -> ds_read_b128 fragment reads <=2-way bank aliasing (free, m136);
//     -> realized via pre-swizzled GLOBAL source + linear LDS dest (global_load_lds rule).
//   K-tiles: NT=16. Tile kt -> buffer kt&1. 4 phases per tile:
//     P0: vmcnt(entry); read A[mh0](8) + B[nh0](4); stage (kt+1).A1 -> buf^1
//     P1: read B[nh1](4)
//     P2: read A[mh1](8);                stage (kt+2).B0,B1 -> buf   (B last read: P1)
//     P3: (reuse B[nh0] regs);           stage (kt+2).A0    -> buf   (A last read: P2)
//   each phase: [reads/stage] barrier; lgkmcnt(0); setprio(1); 16 MFMA; setprio(0); barrier
//   Entry wait: vmcnt(6) (3 half-tiles = 6 loads stay in flight); vmcnt(0) only at kt=NT-1.
//   Every LDS overwrite is barrier-separated from its last reader (strict safety).
template<int NSIZE, int EPI>
__global__ __launch_bounds__(512, 2) void gemm256(
    const unsigned short* __restrict__ A,
    const unsigned short* __restrict__ Bt,
    const float* __restrict__ bias,
    const float* __restrict__ resid,
    unsigned short* __restrict__ out_bf,
    float* __restrict__ out_f)
{
    constexpr int BK  = 64;
    constexpr int NT  = C_SZ / BK;     // 16
    constexpr int NBX = NSIZE / 256;   // 12 (qkv) or 4 (proj)
    constexpr int NBY = B_SZ / 256;    // 16
    constexpr int NWG = NBX * NBY * T_SZ;   // 768 / 256, both % 8 == 0

    __shared__ __align__(16) unsigned short lds[65536];   // 128 KiB
    // layout (ushort idx): A buf0 [0,16384) buf1 [16384,32768); B buf0 [32768,49152) buf1 [49152,65536)
    // within buf: half0 [0,8192), half1 [8192,16384); row stride 64 ushorts

    // XCD-aware swizzle (T1): contiguous chunk of NWG/8 per XCD; by fastest -> B-panel L2 reuse
    const int bid = blockIdx.x;
    const int swz = (bid & 7) * (NWG >> 3) + (bid >> 3);
    const int by  = swz & (NBY - 1);
    const int tmp = swz >> 4;
    const int bx  = tmp % NBX;
    const int t   = tmp / NBX;
    const int m0  = by * 256;
    const int n0  = bx * 256;

    const int tid  = threadIdx.x;
    const int lane = tid & 63;
    const int w    = tid >> 6;
    const int wm   = w >> 2;        // 0..1: which 128-row A half
    const int wn   = w & 3;         // 0..3: which 64-col B slice
    const int quad = lane >> 4;
    const int l16  = lane & 15;

    // ---- staging slot precompute (2 insts/thread per half-tile) ----
    // slot q = (w*2+i)*64 + lane; byte = q*16; row = q>>3; stored chunk = q&7;
    // fetched data chunk = (q&7) ^ (row&7)  (inverse-swizzled global source)
    const int q0  = w * 128 + lane;
    const int q1  = q0 + 64;
    const int r0  = q0 >> 3, ch0 = (q0 & 7) ^ (r0 & 7);
    const int r1  = q1 >> 3, ch1 = (q1 & 7) ^ (r1 & 7);
    const unsigned short* Abase = A + (size_t)t * C_SZ;
    const unsigned short* Bbase = Bt + (size_t)t * NSIZE * C_SZ;
    const unsigned short* gA0 = Abase + (size_t)(m0 + r0) * (T_SZ * C_SZ) + ch0 * 8;
    const unsigned short* gA1 = Abase + (size_t)(m0 + r1) * (T_SZ * C_SZ) + ch1 * 8;
    const unsigned short* gB0 = Bbase + (size_t)(n0 + r0) * C_SZ + ch0 * 8;
    const unsigned short* gB1 = Bbase + (size_t)(n0 + r1) * C_SZ + ch1 * 8;
    unsigned short* dA0 = &lds[(w * 2 + 0) * 512];          // wave-uniform bases
    unsigned short* dA1 = &lds[(w * 2 + 1) * 512];
    unsigned short* dB0 = &lds[32768 + (w * 2 + 0) * 512];
    unsigned short* dB1 = &lds[32768 + (w * 2 + 1) * 512];

#define STG_A(buf, h, kt) do { \
    async16(gA0 + (size_t)(h) * 128 * (T_SZ * C_SZ) + (kt) * BK, dA0 + (buf) * 16384 + (h) * 8192); \
    async16(gA1 + (size_t)(h) * 128 * (T_SZ * C_SZ) + (kt) * BK, dA1 + (buf) * 16384 + (h) * 8192); \
} while (0)
#define STG_B(buf, h, kt) do { \
    async16(gB0 + (size_t)(h) * 128 * C_SZ + (kt) * BK, dB0 + (buf) * 16384 + (h) * 8192); \
    async16(gB1 + (size_t)(h) * 128 * C_SZ + (kt) * BK, dB1 + (buf) * 16384 + (h) * 8192); \
} while (0)

    // ---- fragment read bases ----
    // A frag (mfrag, ks): row R = mfrag*16 + l16 in half wm; data chunk = ks*4+quad;
    // stored chunk = data ^ (R&7), R&7 == l16&7
    const int s7   = l16 & 7;
    const int swk0 = ((0 * 4 + quad) ^ s7) * 8;   // ushort offset within row, ks=0
    const int swk1 = ((1 * 4 + quad) ^ s7) * 8;   // ks=1
    const unsigned short* aR = &lds[wm * 8192 + l16 * 64];
    const unsigned short* bR = &lds[32768 + (wn >> 1) * 8192 + ((wn & 1) * 64 + l16) * 64];

#define LD_A(buf, mh) do { \
    _Pragma("unroll") \
    for (int mi = 0; mi < 4; ++mi) { \
        af[mi][0] = *(const s16x8*)(aR + (buf) * 16384 + ((mh) * 4 + mi) * 1024 + swk0); \
        af[mi][1] = *(const s16x8*)(aR + (buf) * 16384 + ((mh) * 4 + mi) * 1024 + swk1); \
    } \
} while (0)
#define LD_B(buf, nh, dst) do { \
    _Pragma("unroll") \
    for (int ni = 0; ni < 2; ++ni) { \
        dst[ni][0] = *(const s16x8*)(bR + (buf) * 16384 + ((nh) * 2 + ni) * 1024 + swk0); \
        dst[ni][1] = *(const s16x8*)(bR + (buf) * 16384 + ((nh) * 2 + ni) * 1024 + swk1); \
    } \
} while (0)
#define MM(mh, nh, bsrc) do { \
    _Pragma("unroll") \
    for (int mi = 0; mi < 4; ++mi) \
    _Pragma("unroll") \
    for (int ni = 0; ni < 2; ++ni) { \
        acc[(mh) * 4 + mi][(nh) * 2 + ni] = __builtin_amdgcn_mfma_f32_16x16x32_bf16( \
            af[mi][0], bsrc[ni][0], acc[(mh) * 4 + mi][(nh) * 2 + ni], 0, 0, 0); \
        acc[(mh) * 4 + mi][(nh) * 2 + ni] = __builtin_amdgcn_mfma_f32_16x16x32_bf16( \
            af[mi][1], bsrc[ni][1], acc[(mh) * 4 + mi][(nh) * 2 + ni], 0, 0, 0); \
    } \
} while (0)
#define WAITK() do { \
    asm volatile("s_waitcnt lgkmcnt(0)"); \
    __builtin_amdgcn_sched_barrier(0); \
} while (0)
#define KTILE(buf, kt, SP0, SP23, VMC) do { \
    /* P0 */ \
    asm volatile("s_waitcnt vmcnt(" #VMC ")"); \
    __builtin_amdgcn_sched_barrier(0); \
    LD_A(buf, 0); LD_B(buf, 0, bq0); \
    if (SP0) STG_A((buf) ^ 1, 1, (kt) + 1); \
    __builtin_amdgcn_s_barrier(); \
    WAITK(); \
    __builtin_amdgcn_s_setprio(1); MM(0, 0, bq0); __builtin_amdgcn_s_setprio(0); \
    __builtin_amdgcn_s_barrier(); \
    /* P1 */ \
    LD_B(buf, 1, bq1); \
    __builtin_amdgcn_s_barrier(); \
    WAITK(); \
    __builtin_amdgcn_s_setprio(1); MM(0, 1, bq1); __builtin_amdgcn_s_setprio(0); \
    __builtin_amdgcn_s_barrier(); \
    /* P2 */ \
    LD_A(buf, 1); \
    if (SP23) { STG_B(buf, 0, (kt) + 2); STG_B(buf, 1, (kt) + 2); } \
    __builtin_amdgcn_s_barrier(); \
    WAITK(); \
    __builtin_amdgcn_s_setprio(1); MM(1, 1, bq1); __builtin_amdgcn_s_setprio(0); \
    __builtin_amdgcn_s_barrier(); \
    /* P3 */ \
    if (SP23) STG_A(buf, 0, (kt) + 2); \
    __builtin_amdgcn_s_barrier(); \
    WAITK(); \
    __builtin_amdgcn_s_setprio(1); MM(1, 0, bq0); __builtin_amdgcn_s_setprio(0); \
    __builtin_amdgcn_s_barrier(); \
} while (0)

    f32x4 acc[8][4] = {};
    s16x8 af[4][2], bq0[2][2], bq1[2][2];

    // prologue: tile0 (4 halves) + tile1 (B0,B1,A0); wait tile0 (6 loads left in flight);
    // barrier makes tile0 arrival a cross-wave guarantee.
    STG_B(0, 0, 0); STG_B(0, 1, 0); STG_A(0, 0, 0); STG_A(0, 1, 0);
    STG_B(1, 0, 1); STG_B(1, 1, 1); STG_A(1, 0, 1);
    asm volatile("s_waitcnt vmcnt(6)");
    __builtin_amdgcn_sched_barrier(0);
    __builtin_amdgcn_s_barrier();

#pragma clang loop unroll(disable)
    for (int it = 0; it < 7; ++it) {    // tiles 0..13: full staging
        int kt = it * 2;
        KTILE(0, kt, 1, 1, 6);
        KTILE(1, kt + 1, 1, 1, 6);
    }
    KTILE(0, 14, 1, 0, 6);              // stages only (15).A1
    KTILE(1, 15, 0, 0, 0);              // drain

#undef KTILE
#undef WAITK
#undef MM
#undef LD_B
#undef LD_A
#undef STG_B
#undef STG_A

    // Epilogue. C/D layout: col = lane&15, row = quad*4 + reg  [verified m89/m91]
#pragma unroll
    for (int ni = 0; ni < 4; ++ni) {
        int gn = n0 + wn * 64 + ni * 16 + l16;
        float bi = bias[t * NSIZE + gn];
#pragma unroll
        for (int mi = 0; mi < 8; ++mi) {
#pragma unroll
            for (int r = 0; r < 4; ++r) {
                int gm = m0 + wm * 128 + mi * 16 + quad * 4 + r;
                size_t o = (size_t)(gm * T_SZ + t) * NSIZE + gn;
                float v = acc[mi][ni][r] + bi;
                if (EPI == 0) {
                    out_bf[o] = f2bf(v);
                } else {
                    out_f[o] = v + resid[o];
                }
            }
        }
    }
}

// ---------------- cross-task attention: one wave per (b, h) ----------------
// qkv: bf16 [B][T][3C]; ctx: bf16 [B][T][C]
__global__ __launch_bounds__(256) void attn_kernel(const unsigned short* __restrict__ qkv,
                                                   unsigned short* __restrict__ ctx) {
    int wave = threadIdx.x >> 6, lane = threadIdx.x & 63;
    int g = blockIdx.x * 4 + wave;     // [0, B*H)
    int b = g >> 3, h = g & 7;
    int d0 = lane * 2;                 // each lane owns 2 of DH=128 dims

    const unsigned short* base = qkv + (size_t)b * T_SZ * NQKV + h * DH_SZ + d0;
    float qf[4][2], kf[4][2], vf[4][2];
#pragma unroll
    for (int i = 0; i < 4; i++) {
        const unsigned short* p = base + (size_t)i * NQKV;
        qf[i][0] = bf2f(p[0]);          qf[i][1] = bf2f(p[1]);
        kf[i][0] = bf2f(p[C_SZ]);       kf[i][1] = bf2f(p[C_SZ + 1]);
        vf[i][0] = bf2f(p[2 * C_SZ]);   vf[i][1] = bf2f(p[2 * C_SZ + 1]);
    }
    float s[4][4];
#pragma unroll
    for (int i = 0; i < 4; i++)
#pragma unroll
        for (int j = 0; j < 4; j++) {
            float p = qf[i][0] * kf[j][0] + qf[i][1] * kf[j][1];
#pragma unroll
            for (int off = 32; off > 0; off >>= 1) p += __shfl_xor(p, off);
            s[i][j] = p * SCALE_F;
        }
#pragma unroll
    for (int i = 0; i < 4; i++) {
        float m = fmaxf(fmaxf(s[i][0], s[i][1]), fmaxf(s[i][2], s[i][3]));
        float e0 = __expf(s[i][0] - m), e1 = __expf(s[i][1] - m);
        float e2 = __expf(s[i][2] - m), e3 = __expf(s[i][3] - m);
        float inv = 1.0f / (e0 + e1 + e2 + e3);
        s[i][0] = e0 * inv; s[i][1] = e1 * inv; s[i][2] = e2 * inv; s[i][3] = e3 * inv;
    }
#pragma unroll
    for (int i = 0; i < 4; i++) {
        float o0 = s[i][0] * vf[0][0] + s[i][1] * vf[1][0] + s[i][2] * vf[2][0] + s[i][3] * vf[3][0];
        float o1 = s[i][0] * vf[0][1] + s[i][1] * vf[1][1] + s[i][2] * vf[2][1] + s[i][3] * vf[3][1];
        size_t o = (size_t)(b * T_SZ + i) * C_SZ + h * DH_SZ + d0;
        ctx[o] = f2bf(o0); ctx[o + 1] = f2bf(o1);
    }
}

// ---------------- LayerNorm over C, one block per (b,t) row ----------------
__global__ __launch_bounds__(256) void ln_kernel(const float* __restrict__ y,
                                                 const float* __restrict__ gamma,
                                                 const float* __restrict__ beta,
                                                 float* __restrict__ out) {
    int row = blockIdx.x;
    int lane = threadIdx.x & 63, wave = threadIdx.x >> 6;
    float4 v = reinterpret_cast<const float4*>(y + (size_t)row * C_SZ)[threadIdx.x];
    float s  = v.x + v.y + v.z + v.w;
    float ss = v.x * v.x + v.y * v.y + v.z * v.z + v.w * v.w;
#pragma unroll
    for (int off = 32; off > 0; off >>= 1) { s += __shfl_xor(s, off); ss += __shfl_xor(ss, off); }
    __shared__ float red[8];
    if (lane == 0) { red[wave] = s; red[wave + 4] = ss; }
    __syncthreads();
    float S  = red[0] + red[1] + red[2] + red[3];
    float SS = red[4] + red[5] + red[6] + red[7];
    float mean = S * (1.0f / C_SZ);
    float var  = SS * (1.0f / C_SZ) - mean * mean;
    float inv  = rsqrtf(var + 1e-5f);
    float4 g  = reinterpret_cast<const float4*>(gamma)[threadIdx.x];
    float4 be = reinterpret_cast<const float4*>(beta)[threadIdx.x];
    float4 o;
    o.x = (v.x - mean) * inv * g.x + be.x;
    o.y = (v.y - mean) * inv * g.y + be.y;
    o.z = (v.z - mean) * inv * g.z + be.z;
    o.w = (v.w - mean) * inv * g.w + be.w;
    reinterpret_cast<float4*>(out + (size_t)row * C_SZ)[threadIdx.x] = o;
}

extern "C" void kernel_launch(void* const* d_in, const int* in_sizes, int n_in,
                              void* d_out, int out_size, void* d_ws, size_t ws_size,
                              hipStream_t stream) {
    const float* feats = (const float*)d_in[0];   // [B,T,C]
    const float* Wqkv  = (const float*)d_in[1];   // [T,C,3C]
    const float* bqkv  = (const float*)d_in[2];   // [T,3C]
    const float* Wproj = (const float*)d_in[3];   // [T,C,C]
    const float* bproj = (const float*)d_in[4];   // [T,C]
    const float* gamma = (const float*)d_in[5];   // [C]
    const float* beta  = (const float*)d_in[6];   // [C]
    float* out = (float*)d_out;

    // ws layout (bytes):
    //   [0,   33.5M)  feats_bf16  [B,T,C]
    //   [33.5M, 58.7M) WqkvT bf16 [T,3C,C]
    //   [58.7M, 67.1M) WprojT bf16 [T,C,C]
    //   [67.1M, 167.8M) qkv bf16 [B,T,3C]   (later aliased by y fp32 [B,T,C] = 67.1MB)
    //   [167.8M, 201.3M) ctx bf16 [B,T,C]
    char* ws = (char*)d_ws;
    unsigned short* feats_bf = (unsigned short*)(ws);
    unsigned short* wqkv_t   = (unsigned short*)(ws + 33554432);
    unsigned short* wproj_t  = (unsigned short*)(ws + 58720256);
    unsigned short* qkv      = (unsigned short*)(ws + 67108864);
    unsigned short* ctx      = (unsigned short*)(ws + 167772160);
    float* ybuf              = (float*)(ws + 67108864);   // aliases qkv (dead after attn)

    cvt_f32_bf16<<<16384, 256, 0, stream>>>(feats, feats_bf, (B_SZ * T_SZ * C_SZ) / 4);
    transpose_cvt<<<dim3(96, 32, 4), dim3(32, 8), 0, stream>>>(Wqkv, wqkv_t, C_SZ, NQKV);
    transpose_cvt<<<dim3(32, 32, 4), dim3(32, 8), 0, stream>>>(Wproj, wproj_t, C_SZ, C_SZ);

    // QKV: grid = (3072/256)*(4096/256)*4 = 768 blocks of 512
    gemm256<NQKV, 0><<<dim3(768), 512, 0, stream>>>(
        feats_bf, wqkv_t, bqkv, nullptr, qkv, nullptr);

    attn_kernel<<<(B_SZ * H_SZ) / 4, 256, 0, stream>>>(qkv, ctx);

    // proj: grid = (1024/256)*(4096/256)*4 = 256 blocks of 512 (exactly 1/CU)
    gemm256<C_SZ, 1><<<dim3(256), 512, 0, stream>>>(
        ctx, wproj_t, bproj, feats, nullptr, ybuf);

    ln_kernel<<<B_SZ * T_SZ, 256, 0, stream>>>(ybuf, gamma, beta, out);
}

// Round 2
// 425.740 us; speedup vs baseline: 1.0485x; 1.0040x over previous
//
#include <hip/hip_runtime.h>
#include <hip/hip_bf16.h>
#include <cstdint>
#include <cstddef>

// Problem constants
#define B_SZ 4096
#define T_SZ 4
#define C_SZ 1024
#define H_SZ 8
#define DH_SZ 128
#define NQKV 3072                      // 3*C
#define SCALE_F 0.08838834764831845f   // 128^-0.5

typedef float f32x4 __attribute__((ext_vector_type(4)));
typedef short s16x8 __attribute__((ext_vector_type(8)));

static __device__ __forceinline__ float bf2f(unsigned short u) {
    union { unsigned int i; float f; } x; x.i = ((unsigned int)u) << 16; return x.f;
}
static __device__ __forceinline__ unsigned short f2bf(float f) {
    union { unsigned int i; float f; } x; x.f = f;
    unsigned int r = x.i + 0x7FFFu + ((x.i >> 16) & 1u);   // RNE
    return (unsigned short)(r >> 16);
}

// async global->LDS, 16B per lane; lds base must be wave-uniform (HW adds lane*16)
typedef const __attribute__((address_space(1))) void* gas_ptr;
typedef __attribute__((address_space(3))) void* las_ptr;
static __device__ __forceinline__ void async16(const void* g, void* l) {
    __builtin_amdgcn_global_load_lds((gas_ptr)g, (las_ptr)l, 16, 0, 0);
}

// ---------------- elementwise fp32 -> bf16 ----------------
__global__ __launch_bounds__(256) void cvt_f32_bf16(const float* __restrict__ src,
                                                    unsigned short* __restrict__ dst, int n4) {
    int i = blockIdx.x * 256 + threadIdx.x;
    if (i >= n4) return;
    float4 v = reinterpret_cast<const float4*>(src)[i];
    ushort4 o;
    o.x = f2bf(v.x); o.y = f2bf(v.y); o.z = f2bf(v.z); o.w = f2bf(v.w);
    reinterpret_cast<ushort4*>(dst)[i] = o;
}

// ---------------- transpose + convert: src[K][N] fp32 -> dst[N][K] bf16 (per z=task) --------
__global__ __launch_bounds__(256) void transpose_cvt(const float* __restrict__ src,
                                                     unsigned short* __restrict__ dst,
                                                     int K, int N) {
    __shared__ float tile[32][33];
    const float* s = src + (size_t)blockIdx.z * K * N;
    unsigned short* d = dst + (size_t)blockIdx.z * K * N;
    int n0 = blockIdx.x * 32, k0 = blockIdx.y * 32;
    int tx = threadIdx.x, ty = threadIdx.y;
#pragma unroll
    for (int i = 0; i < 4; i++) {
        int k = k0 + ty + i * 8;
        tile[ty + i * 8][tx] = s[(size_t)k * N + n0 + tx];
    }
    __syncthreads();
#pragma unroll
    for (int i = 0; i < 4; i++) {
        int n = n0 + ty + i * 8;
        d[(size_t)n * K + k0 + tx] = f2bf(tile[tx][ty + i * 8]);
    }
}

// ---------------- 256x256 8-phase bf16 MFMA GEMM (T2+T3+T4+T5 stack) ----------------
// A: bf16, row m of task t at A + t*C + m*(T*C), K = C = 1024
// Bt: bf16 [T][NSIZE][K] (B transposed), bias: fp32 [T][NSIZE]
// EPI 0: out_bf[(m*T+t)*NSIZE + n] = bf16(acc + bias)
// EPI 1: out_f [(m*T+t)*NSIZE + n] = acc + bias + resid[...]
//
// Structure (per guide §5 template, m194-m201 / m248):
//   BM=BN=256, BK=64, 8 waves (2M x 4N), 512 thr, LDS 128 KiB = 2buf x {A 32KB, B 32KB}.
//   Each buf half-tile = 128 rows x 64 cols bf16 = 16 KiB = 2 global_load_lds_dwordx4/thread.
//   LDS chunk swizzle: stored_chunk = data_chunk ^ (row&7)  (16B chunks, 8/row)
//     -> ds_read_b128 fragment reads <=2-way bank aliasing (free, m136);
//     -> realized via pre-swizzled GLOBAL source + linear LDS dest (global_load_lds rule).
//   K-tiles: NT=16. Tile kt -> buffer kt&1. 4 phases per tile:
//     P0: vmcnt(entry); read A[mh0](8) + B[nh0](4); stage (kt+1).A1 -> buf^1
//     P1: read B[nh1](4)
//     P2: read A[mh1](8);                stage (kt+2).B0,B1 -> buf   (B last read: P1)
//     P3: (reuse B[nh0] regs);           stage (kt+2).A0    -> buf   (A last read: P2)
//   each phase: [reads/stage] barrier; lgkmcnt(0); setprio(1); 16 MFMA; setprio(0); barrier
//   Entry wait: vmcnt(6) (3 half-tiles = 6 loads stay in flight); vmcnt(0) only at kt=NT-1.
//   Every LDS overwrite is barrier-separated from its last reader (strict safety).
//
// NOTE launch_bounds: LDS=128KiB already caps at 1 block/CU (2 waves/SIMD). min-waves
// MUST be 1: acc[8][4] f32x4 alone = 128 VGPR; (512,2) capped VGPR at 128 -> scratch
// spills (round 1: VGPR_Count=128, WRITE_SIZE 170MB vs 101MB output = spill traffic).
template<int NSIZE, int EPI>
__global__ __launch_bounds__(512, 1) void gemm256(
    const unsigned short* __restrict__ A,
    const unsigned short* __restrict__ Bt,
    const float* __restrict__ bias,
    const float* __restrict__ resid,
    unsigned short* __restrict__ out_bf,
    float* __restrict__ out_f)
{
    constexpr int BK  = 64;
    constexpr int NT  = C_SZ / BK;     // 16
    constexpr int NBX = NSIZE / 256;   // 12 (qkv) or 4 (proj)
    constexpr int NBY = B_SZ / 256;    // 16
    constexpr int NWG = NBX * NBY * T_SZ;   // 768 / 256, both % 8 == 0

    __shared__ __align__(16) unsigned short lds[65536];   // 128 KiB
    // layout (ushort idx): A buf0 [0,16384) buf1 [16384,32768); B buf0 [32768,49152) buf1 [49152,65536)
    // within buf: half0 [0,8192), half1 [8192,16384); row stride 64 ushorts

    // XCD-aware swizzle (T1): contiguous chunk of NWG/8 per XCD; by fastest -> B-panel L2 reuse
    const int bid = blockIdx.x;
    const int swz = (bid & 7) * (NWG >> 3) + (bid >> 3);
    const int by  = swz & (NBY - 1);
    const int tmp = swz >> 4;
    const int bx  = tmp % NBX;
    const int t   = tmp / NBX;
    const int m0  = by * 256;
    const int n0  = bx * 256;

    const int tid  = threadIdx.x;
    const int lane = tid & 63;
    const int w    = tid >> 6;
    const int wm   = w >> 2;        // 0..1: which 128-row A half
    const int wn   = w & 3;         // 0..3: which 64-col B slice
    const int quad = lane >> 4;
    const int l16  = lane & 15;

    // ---- staging slot precompute (2 insts/thread per half-tile) ----
    // slot q = (w*2+i)*64 + lane; byte = q*16; row = q>>3; stored chunk = q&7;
    // fetched data chunk = (q&7) ^ (row&7)  (inverse-swizzled global source)
    const int q0  = w * 128 + lane;
    const int q1  = q0 + 64;
    const int r0  = q0 >> 3, ch0 = (q0 & 7) ^ (r0 & 7);
    const int r1  = q1 >> 3, ch1 = (q1 & 7) ^ (r1 & 7);
    const unsigned short* Abase = A + (size_t)t * C_SZ;
    const unsigned short* Bbase = Bt + (size_t)t * NSIZE * C_SZ;
    const unsigned short* gA0 = Abase + (size_t)(m0 + r0) * (T_SZ * C_SZ) + ch0 * 8;
    const unsigned short* gA1 = Abase + (size_t)(m0 + r1) * (T_SZ * C_SZ) + ch1 * 8;
    const unsigned short* gB0 = Bbase + (size_t)(n0 + r0) * C_SZ + ch0 * 8;
    const unsigned short* gB1 = Bbase + (size_t)(n0 + r1) * C_SZ + ch1 * 8;
    unsigned short* dA0 = &lds[(w * 2 + 0) * 512];          // wave-uniform bases
    unsigned short* dA1 = &lds[(w * 2 + 1) * 512];
    unsigned short* dB0 = &lds[32768 + (w * 2 + 0) * 512];
    unsigned short* dB1 = &lds[32768 + (w * 2 + 1) * 512];

#define STG_A(buf, h, kt) do { \
    async16(gA0 + (size_t)(h) * 128 * (T_SZ * C_SZ) + (kt) * BK, dA0 + (buf) * 16384 + (h) * 8192); \
    async16(gA1 + (size_t)(h) * 128 * (T_SZ * C_SZ) + (kt) * BK, dA1 + (buf) * 16384 + (h) * 8192); \
} while (0)
#define STG_B(buf, h, kt) do { \
    async16(gB0 + (size_t)(h) * 128 * C_SZ + (kt) * BK, dB0 + (buf) * 16384 + (h) * 8192); \
    async16(gB1 + (size_t)(h) * 128 * C_SZ + (kt) * BK, dB1 + (buf) * 16384 + (h) * 8192); \
} while (0)

    // ---- fragment read bases ----
    // A frag (mfrag, ks): row R = mfrag*16 + l16 in half wm; data chunk = ks*4+quad;
    // stored chunk = data ^ (R&7), R&7 == l16&7
    const int s7   = l16 & 7;
    const int swk0 = ((0 * 4 + quad) ^ s7) * 8;   // ushort offset within row, ks=0
    const int swk1 = ((1 * 4 + quad) ^ s7) * 8;   // ks=1
    const unsigned short* aR = &lds[wm * 8192 + l16 * 64];
    const unsigned short* bR = &lds[32768 + (wn >> 1) * 8192 + ((wn & 1) * 64 + l16) * 64];

#define LD_A(buf, mh) do { \
    _Pragma("unroll") \
    for (int mi = 0; mi < 4; ++mi) { \
        af[mi][0] = *(const s16x8*)(aR + (buf) * 16384 + ((mh) * 4 + mi) * 1024 + swk0); \
        af[mi][1] = *(const s16x8*)(aR + (buf) * 16384 + ((mh) * 4 + mi) * 1024 + swk1); \
    } \
} while (0)
#define LD_B(buf, nh, dst) do { \
    _Pragma("unroll") \
    for (int ni = 0; ni < 2; ++ni) { \
        dst[ni][0] = *(const s16x8*)(bR + (buf) * 16384 + ((nh) * 2 + ni) * 1024 + swk0); \
        dst[ni][1] = *(const s16x8*)(bR + (buf) * 16384 + ((nh) * 2 + ni) * 1024 + swk1); \
    } \
} while (0)
#define MM(mh, nh, bsrc) do { \
    _Pragma("unroll") \
    for (int mi = 0; mi < 4; ++mi) \
    _Pragma("unroll") \
    for (int ni = 0; ni < 2; ++ni) { \
        acc[(mh) * 4 + mi][(nh) * 2 + ni] = __builtin_amdgcn_mfma_f32_16x16x32_bf16( \
            af[mi][0], bsrc[ni][0], acc[(mh) * 4 + mi][(nh) * 2 + ni], 0, 0, 0); \
        acc[(mh) * 4 + mi][(nh) * 2 + ni] = __builtin_amdgcn_mfma_f32_16x16x32_bf16( \
            af[mi][1], bsrc[ni][1], acc[(mh) * 4 + mi][(nh) * 2 + ni], 0, 0, 0); \
    } \
} while (0)
#define WAITK() do { \
    asm volatile("s_waitcnt lgkmcnt(0)"); \
    __builtin_amdgcn_sched_barrier(0); \
} while (0)
#define KTILE(buf, kt, SP0, SP23, VMC) do { \
    /* P0 */ \
    asm volatile("s_waitcnt vmcnt(" #VMC ")"); \
    __builtin_amdgcn_sched_barrier(0); \
    LD_A(buf, 0); LD_B(buf, 0, bq0); \
    if (SP0) STG_A((buf) ^ 1, 1, (kt) + 1); \
    __builtin_amdgcn_s_barrier(); \
    WAITK(); \
    __builtin_amdgcn_s_setprio(1); MM(0, 0, bq0); __builtin_amdgcn_s_setprio(0); \
    __builtin_amdgcn_s_barrier(); \
    /* P1 */ \
    LD_B(buf, 1, bq1); \
    __builtin_amdgcn_s_barrier(); \
    WAITK(); \
    __builtin_amdgcn_s_setprio(1); MM(0, 1, bq1); __builtin_amdgcn_s_setprio(0); \
    __builtin_amdgcn_s_barrier(); \
    /* P2 */ \
    LD_A(buf, 1); \
    if (SP23) { STG_B(buf, 0, (kt) + 2); STG_B(buf, 1, (kt) + 2); } \
    __builtin_amdgcn_s_barrier(); \
    WAITK(); \
    __builtin_amdgcn_s_setprio(1); MM(1, 1, bq1); __builtin_amdgcn_s_setprio(0); \
    __builtin_amdgcn_s_barrier(); \
    /* P3 */ \
    if (SP23) STG_A(buf, 0, (kt) + 2); \
    __builtin_amdgcn_s_barrier(); \
    WAITK(); \
    __builtin_amdgcn_s_setprio(1); MM(1, 0, bq0); __builtin_amdgcn_s_setprio(0); \
    __builtin_amdgcn_s_barrier(); \
} while (0)

    f32x4 acc[8][4] = {};
    s16x8 af[4][2], bq0[2][2], bq1[2][2];

    // prologue: tile0 (4 halves) + tile1 (B0,B1,A0); wait tile0 (6 loads left in flight);
    // barrier makes tile0 arrival a cross-wave guarantee.
    STG_B(0, 0, 0); STG_B(0, 1, 0); STG_A(0, 0, 0); STG_A(0, 1, 0);
    STG_B(1, 0, 1); STG_B(1, 1, 1); STG_A(1, 0, 1);
    asm volatile("s_waitcnt vmcnt(6)");
    __builtin_amdgcn_sched_barrier(0);
    __builtin_amdgcn_s_barrier();

#pragma clang loop unroll(disable)
    for (int it = 0; it < 7; ++it) {    // tiles 0..13: full staging
        int kt = it * 2;
        KTILE(0, kt, 1, 1, 6);
        KTILE(1, kt + 1, 1, 1, 6);
    }
    KTILE(0, 14, 1, 0, 6);              // stages only (15).A1
    KTILE(1, 15, 0, 0, 0);              // drain

#undef KTILE
#undef WAITK
#undef MM
#undef LD_B
#undef LD_A
#undef STG_B
#undef STG_A

    // Epilogue. C/D layout: col = lane&15, row = quad*4 + reg  [verified m89/m91]
#pragma unroll
    for (int ni = 0; ni < 4; ++ni) {
        int gn = n0 + wn * 64 + ni * 16 + l16;
        float bi = bias[t * NSIZE + gn];
#pragma unroll
        for (int mi = 0; mi < 8; ++mi) {
#pragma unroll
            for (int r = 0; r < 4; ++r) {
                int gm = m0 + wm * 128 + mi * 16 + quad * 4 + r;
                size_t o = (size_t)(gm * T_SZ + t) * NSIZE + gn;
                float v = acc[mi][ni][r] + bi;
                if (EPI == 0) {
                    out_bf[o] = f2bf(v);
                } else {
                    out_f[o] = v + resid[o];
                }
            }
        }
    }
}

// ---------------- cross-task attention: one wave per (b, h) ----------------
// qkv: bf16 [B][T][3C]; ctx: bf16 [B][T][C]
__global__ __launch_bounds__(256) void attn_kernel(const unsigned short* __restrict__ qkv,
                                                   unsigned short* __restrict__ ctx) {
    int wave = threadIdx.x >> 6, lane = threadIdx.x & 63;
    int g = blockIdx.x * 4 + wave;     // [0, B*H)
    int b = g >> 3, h = g & 7;
    int d0 = lane * 2;                 // each lane owns 2 of DH=128 dims

    const unsigned short* base = qkv + (size_t)b * T_SZ * NQKV + h * DH_SZ + d0;
    float qf[4][2], kf[4][2], vf[4][2];
#pragma unroll
    for (int i = 0; i < 4; i++) {
        const unsigned short* p = base + (size_t)i * NQKV;
        qf[i][0] = bf2f(p[0]);          qf[i][1] = bf2f(p[1]);
        kf[i][0] = bf2f(p[C_SZ]);       kf[i][1] = bf2f(p[C_SZ + 1]);
        vf[i][0] = bf2f(p[2 * C_SZ]);   vf[i][1] = bf2f(p[2 * C_SZ + 1]);
    }
    float s[4][4];
#pragma unroll
    for (int i = 0; i < 4; i++)
#pragma unroll
        for (int j = 0; j < 4; j++) {
            float p = qf[i][0] * kf[j][0] + qf[i][1] * kf[j][1];
#pragma unroll
            for (int off = 32; off > 0; off >>= 1) p += __shfl_xor(p, off);
            s[i][j] = p * SCALE_F;
        }
#pragma unroll
    for (int i = 0; i < 4; i++) {
        float m = fmaxf(fmaxf(s[i][0], s[i][1]), fmaxf(s[i][2], s[i][3]));
        float e0 = __expf(s[i][0] - m), e1 = __expf(s[i][1] - m);
        float e2 = __expf(s[i][2] - m), e3 = __expf(s[i][3] - m);
        float inv = 1.0f / (e0 + e1 + e2 + e3);
        s[i][0] = e0 * inv; s[i][1] = e1 * inv; s[i][2] = e2 * inv; s[i][3] = e3 * inv;
    }
#pragma unroll
    for (int i = 0; i < 4; i++) {
        float o0 = s[i][0] * vf[0][0] + s[i][1] * vf[1][0] + s[i][2] * vf[2][0] + s[i][3] * vf[3][0];
        float o1 = s[i][0] * vf[0][1] + s[i][1] * vf[1][1] + s[i][2] * vf[2][1] + s[i][3] * vf[3][1];
        size_t o = (size_t)(b * T_SZ + i) * C_SZ + h * DH_SZ + d0;
        ctx[o] = f2bf(o0); ctx[o + 1] = f2bf(o1);
    }
}

// ---------------- LayerNorm over C, one block per (b,t) row ----------------
__global__ __launch_bounds__(256) void ln_kernel(const float* __restrict__ y,
                                                 const float* __restrict__ gamma,
                                                 const float* __restrict__ beta,
                                                 float* __restrict__ out) {
    int row = blockIdx.x;
    int lane = threadIdx.x & 63, wave = threadIdx.x >> 6;
    float4 v = reinterpret_cast<const float4*>(y + (size_t)row * C_SZ)[threadIdx.x];
    float s  = v.x + v.y + v.z + v.w;
    float ss = v.x * v.x + v.y * v.y + v.z * v.z + v.w * v.w;
#pragma unroll
    for (int off = 32; off > 0; off >>= 1) { s += __shfl_xor(s, off); ss += __shfl_xor(ss, off); }
    __shared__ float red[8];
    if (lane == 0) { red[wave] = s; red[wave + 4] = ss; }
    __syncthreads();
    float S  = red[0] + red[1] + red[2] + red[3];
    float SS = red[4] + red[5] + red[6] + red[7];
    float mean = S * (1.0f / C_SZ);
    float var  = SS * (1.0f / C_SZ) - mean * mean;
    float inv  = rsqrtf(var + 1e-5f);
    float4 g  = reinterpret_cast<const float4*>(gamma)[threadIdx.x];
    float4 be = reinterpret_cast<const float4*>(beta)[threadIdx.x];
    float4 o;
    o.x = (v.x - mean) * inv * g.x + be.x;
    o.y = (v.y - mean) * inv * g.y + be.y;
    o.z = (v.z - mean) * inv * g.z + be.z;
    o.w = (v.w - mean) * inv * g.w + be.w;
    reinterpret_cast<float4*>(out + (size_t)row * C_SZ)[threadIdx.x] = o;
}

extern "C" void kernel_launch(void* const* d_in, const int* in_sizes, int n_in,
                              void* d_out, int out_size, void* d_ws, size_t ws_size,
                              hipStream_t stream) {
    const float* feats = (const float*)d_in[0];   // [B,T,C]
    const float* Wqkv  = (const float*)d_in[1];   // [T,C,3C]
    const float* bqkv  = (const float*)d_in[2];   // [T,3C]
    const float* Wproj = (const float*)d_in[3];   // [T,C,C]
    const float* bproj = (const float*)d_in[4];   // [T,C]
    const float* gamma = (const float*)d_in[5];   // [C]
    const float* beta  = (const float*)d_in[6];   // [C]
    float* out = (float*)d_out;

    // ws layout (bytes):
    //   [0,   33.5M)  feats_bf16  [B,T,C]
    //   [33.5M, 58.7M) WqkvT bf16 [T,3C,C]
    //   [58.7M, 67.1M) WprojT bf16 [T,C,C]
    //   [67.1M, 167.8M) qkv bf16 [B,T,3C]   (later aliased by y fp32 [B,T,C] = 67.1MB)
    //   [167.8M, 201.3M) ctx bf16 [B,T,C]
    char* ws = (char*)d_ws;
    unsigned short* feats_bf = (unsigned short*)(ws);
    unsigned short* wqkv_t   = (unsigned short*)(ws + 33554432);
    unsigned short* wproj_t  = (unsigned short*)(ws + 58720256);
    unsigned short* qkv      = (unsigned short*)(ws + 67108864);
    unsigned short* ctx      = (unsigned short*)(ws + 167772160);
    float* ybuf              = (float*)(ws + 67108864);   // aliases qkv (dead after attn)

    cvt_f32_bf16<<<16384, 256, 0, stream>>>(feats, feats_bf, (B_SZ * T_SZ * C_SZ) / 4);
    transpose_cvt<<<dim3(96, 32, 4), dim3(32, 8), 0, stream>>>(Wqkv, wqkv_t, C_SZ, NQKV);
    transpose_cvt<<<dim3(32, 32, 4), dim3(32, 8), 0, stream>>>(Wproj, wproj_t, C_SZ, C_SZ);

    // QKV: grid = (3072/256)*(4096/256)*4 = 768 blocks of 512
    gemm256<NQKV, 0><<<dim3(768), 512, 0, stream>>>(
        feats_bf, wqkv_t, bqkv, nullptr, qkv, nullptr);

    attn_kernel<<<(B_SZ * H_SZ) / 4, 256, 0, stream>>>(qkv, ctx);

    // proj: grid = (1024/256)*(4096/256)*4 = 256 blocks of 512 (exactly 1/CU)
    gemm256<C_SZ, 1><<<dim3(256), 512, 0, stream>>>(
        ctx, wproj_t, bproj, feats, nullptr, ybuf);

    ln_kernel<<<B_SZ * T_SZ, 256, 0, stream>>>(ybuf, gamma, beta, out);
}

// Round 3
// 417.761 us; speedup vs baseline: 1.0685x; 1.0191x over previous
//
#include <hip/hip_runtime.h>
#include <hip/hip_bf16.h>
#include <cstdint>
#include <cstddef>

// Problem constants
#define B_SZ 4096
#define T_SZ 4
#define C_SZ 1024
#define H_SZ 8
#define DH_SZ 128
#define NQKV 3072                      // 3*C
#define SCALE_F 0.08838834764831845f   // 128^-0.5

typedef float f32x4 __attribute__((ext_vector_type(4)));
typedef short s16x8 __attribute__((ext_vector_type(8)));

static __device__ __forceinline__ float bf2f(unsigned short u) {
    union { unsigned int i; float f; } x; x.i = ((unsigned int)u) << 16; return x.f;
}
static __device__ __forceinline__ unsigned short f2bf(float f) {
    union { unsigned int i; float f; } x; x.f = f;
    unsigned int r = x.i + 0x7FFFu + ((x.i >> 16) & 1u);   // RNE
    return (unsigned short)(r >> 16);
}

// async global->LDS, 16B per lane; lds base must be wave-uniform (HW adds lane*16)
typedef const __attribute__((address_space(1))) void* gas_ptr;
typedef __attribute__((address_space(3))) void* las_ptr;
static __device__ __forceinline__ void async16(const void* g, void* l) {
    __builtin_amdgcn_global_load_lds((gas_ptr)g, (las_ptr)l, 16, 0, 0);
}

// ---------------- elementwise fp32 -> bf16 ----------------
__global__ __launch_bounds__(256) void cvt_f32_bf16(const float* __restrict__ src,
                                                    unsigned short* __restrict__ dst, int n4) {
    int i = blockIdx.x * 256 + threadIdx.x;
    if (i >= n4) return;
    float4 v = reinterpret_cast<const float4*>(src)[i];
    ushort4 o;
    o.x = f2bf(v.x); o.y = f2bf(v.y); o.z = f2bf(v.z); o.w = f2bf(v.w);
    reinterpret_cast<ushort4*>(dst)[i] = o;
}

// ---------------- transpose + convert: src[K][N] fp32 -> dst[N][K] bf16 (per z=task) --------
__global__ __launch_bounds__(256) void transpose_cvt(const float* __restrict__ src,
                                                     unsigned short* __restrict__ dst,
                                                     int K, int N) {
    __shared__ float tile[32][33];
    const float* s = src + (size_t)blockIdx.z * K * N;
    unsigned short* d = dst + (size_t)blockIdx.z * K * N;
    int n0 = blockIdx.x * 32, k0 = blockIdx.y * 32;
    int tx = threadIdx.x, ty = threadIdx.y;
#pragma unroll
    for (int i = 0; i < 4; i++) {
        int k = k0 + ty + i * 8;
        tile[ty + i * 8][tx] = s[(size_t)k * N + n0 + tx];
    }
    __syncthreads();
#pragma unroll
    for (int i = 0; i < 4; i++) {
        int n = n0 + ty + i * 8;
        d[(size_t)n * K + k0 + tx] = f2bf(tile[tx][ty + i * 8]);
    }
}

// ---------------- 256x256 8-phase bf16 MFMA GEMM (T1+T2+T3+T4+T5) ----------------
// A: bf16, row m of task t at A + t*C + m*(T*C), K = C = 1024
// Bt: bf16 [T][NSIZE][K] (B transposed), bias: fp32 [T][NSIZE]
// EPI 0: out_bf[(m*T+t)*NSIZE + n] = bf16(acc + bias)
// EPI 1: out_f [(m*T+t)*NSIZE + n] = acc + bias + resid[...]
//
// BM=BN=256, BK=64, 8 waves (2M x 4N), 512 thr, LDS 128 KiB dbuf, swizzled chunks.
//
// ROUND-3 restructure: ONE barrier per phase (was 2) + reads strictly AFTER the
// P0 {all-waves vmcnt(6); barrier} pair.
//   - Round-2 issued P0 ds_reads before the barrier: only MY wave's vmcnt had
//     retired, but the tile is staged by ALL waves -> latent race (masked by slack).
//     Now: vmcnt -> barrier -> reads. Correct by construction.
//   - The dropped mid-phase barrier was unnecessary: the only cross-wave hazard is
//     {staging-write vs LDS-read}. Each STG below targets a region whose last reads
//     were lgkm-retired in an EARLIER phase, with >=1 intervening barrier:
//       P0 STG_A(buf^1,A1,kt+1): buf^1.A1 last read prev-tile P2 (2 bars back)
//       P2 STG_B(buf,*,kt+2):    buf.B1 last read P1 (retired at P1 WAITK, bar P2)
//                                buf.B0 last read P0 (bars P1,P2)
//       P3 STG_A(buf,A0,kt+2):   buf.A0 last read P0 (bars P1,P2,P3)
//   - Single barrier/phase lets waves skew across phases (reads vs MFMA role-split)
//     -> setprio arbitration becomes meaningful (T5 mechanism, m218b).
// vmcnt(6) steady state: after P0 wait, in-flight = {B0B1,A0}(kt+1)=6; tile stages
// A1(kt+1)@P0, B0B1(kt+2)@P2, A0(kt+2)@P3 -> 14; next P0 retires 8 = tile kt+1. ✓
template<int NSIZE, int EPI>
__global__ __launch_bounds__(512, 1) void gemm256(
    const unsigned short* __restrict__ A,
    const unsigned short* __restrict__ Bt,
    const float* __restrict__ bias,
    const float* __restrict__ resid,
    unsigned short* __restrict__ out_bf,
    float* __restrict__ out_f)
{
    constexpr int BK  = 64;
    constexpr int NBX = NSIZE / 256;   // 12 (qkv) or 4 (proj)
    constexpr int NBY = B_SZ / 256;    // 16
    constexpr int NWG = NBX * NBY * T_SZ;   // 768 / 256, both % 8 == 0

    __shared__ __align__(16) unsigned short lds[65536];   // 128 KiB
    // layout (ushort idx): A buf0 [0,16384) buf1 [16384,32768); B buf0 [32768,49152) buf1 [49152,65536)
    // within buf: half0 [0,8192), half1 [8192,16384); row stride 64 ushorts

    // XCD-aware swizzle (T1): contiguous chunk of NWG/8 per XCD; by fastest -> B-panel L2 reuse
    const int bid = blockIdx.x;
    const int swz = (bid & 7) * (NWG >> 3) + (bid >> 3);
    const int by  = swz & (NBY - 1);
    const int tmp = swz >> 4;
    const int bx  = tmp % NBX;
    const int t   = tmp / NBX;
    const int m0  = by * 256;
    const int n0  = bx * 256;

    const int tid  = threadIdx.x;
    const int lane = tid & 63;
    const int w    = tid >> 6;
    const int wm   = w >> 2;        // 0..1: which 128-row A half
    const int wn   = w & 3;         // 0..3: which 64-col B slice
    const int quad = lane >> 4;
    const int l16  = lane & 15;

    // ---- staging slot precompute (2 insts/thread per half-tile) ----
    // slot q = (w*2+i)*64 + lane; byte = q*16; row = q>>3; stored chunk = q&7;
    // fetched data chunk = (q&7) ^ (row&7)  (inverse-swizzled global source)
    const int q0  = w * 128 + lane;
    const int q1  = q0 + 64;
    const int r0  = q0 >> 3, ch0 = (q0 & 7) ^ (r0 & 7);
    const int r1  = q1 >> 3, ch1 = (q1 & 7) ^ (r1 & 7);
    const unsigned short* Abase = A + (size_t)t * C_SZ;
    const unsigned short* Bbase = Bt + (size_t)t * NSIZE * C_SZ;
    const unsigned short* gA0 = Abase + (size_t)(m0 + r0) * (T_SZ * C_SZ) + ch0 * 8;
    const unsigned short* gA1 = Abase + (size_t)(m0 + r1) * (T_SZ * C_SZ) + ch1 * 8;
    const unsigned short* gB0 = Bbase + (size_t)(n0 + r0) * C_SZ + ch0 * 8;
    const unsigned short* gB1 = Bbase + (size_t)(n0 + r1) * C_SZ + ch1 * 8;
    unsigned short* dA0 = &lds[(w * 2 + 0) * 512];          // wave-uniform bases
    unsigned short* dA1 = &lds[(w * 2 + 1) * 512];
    unsigned short* dB0 = &lds[32768 + (w * 2 + 0) * 512];
    unsigned short* dB1 = &lds[32768 + (w * 2 + 1) * 512];

#define STG_A(buf, h, kt) do { \
    async16(gA0 + (size_t)(h) * 128 * (T_SZ * C_SZ) + (kt) * BK, dA0 + (buf) * 16384 + (h) * 8192); \
    async16(gA1 + (size_t)(h) * 128 * (T_SZ * C_SZ) + (kt) * BK, dA1 + (buf) * 16384 + (h) * 8192); \
} while (0)
#define STG_B(buf, h, kt) do { \
    async16(gB0 + (size_t)(h) * 128 * C_SZ + (kt) * BK, dB0 + (buf) * 16384 + (h) * 8192); \
    async16(gB1 + (size_t)(h) * 128 * C_SZ + (kt) * BK, dB1 + (buf) * 16384 + (h) * 8192); \
} while (0)

    // ---- fragment read bases ----
    // A frag (mfrag, ks): row R = mfrag*16 + l16 in half wm; data chunk = ks*4+quad;
    // stored chunk = data ^ (R&7), R&7 == l16&7
    const int s7   = l16 & 7;
    const int swk0 = ((0 * 4 + quad) ^ s7) * 8;   // ushort offset within row, ks=0
    const int swk1 = ((1 * 4 + quad) ^ s7) * 8;   // ks=1
    const unsigned short* aR = &lds[wm * 8192 + l16 * 64];
    const unsigned short* bR = &lds[32768 + (wn >> 1) * 8192 + ((wn & 1) * 64 + l16) * 64];

#define LD_A(buf, mh) do { \
    _Pragma("unroll") \
    for (int mi = 0; mi < 4; ++mi) { \
        af[mi][0] = *(const s16x8*)(aR + (buf) * 16384 + ((mh) * 4 + mi) * 1024 + swk0); \
        af[mi][1] = *(const s16x8*)(aR + (buf) * 16384 + ((mh) * 4 + mi) * 1024 + swk1); \
    } \
} while (0)
#define LD_B(buf, nh, dst) do { \
    _Pragma("unroll") \
    for (int ni = 0; ni < 2; ++ni) { \
        dst[ni][0] = *(const s16x8*)(bR + (buf) * 16384 + ((nh) * 2 + ni) * 1024 + swk0); \
        dst[ni][1] = *(const s16x8*)(bR + (buf) * 16384 + ((nh) * 2 + ni) * 1024 + swk1); \
    } \
} while (0)
#define MM(mh, nh, bsrc) do { \
    _Pragma("unroll") \
    for (int mi = 0; mi < 4; ++mi) \
    _Pragma("unroll") \
    for (int ni = 0; ni < 2; ++ni) { \
        acc[(mh) * 4 + mi][(nh) * 2 + ni] = __builtin_amdgcn_mfma_f32_16x16x32_bf16( \
            af[mi][0], bsrc[ni][0], acc[(mh) * 4 + mi][(nh) * 2 + ni], 0, 0, 0); \
        acc[(mh) * 4 + mi][(nh) * 2 + ni] = __builtin_amdgcn_mfma_f32_16x16x32_bf16( \
            af[mi][1], bsrc[ni][1], acc[(mh) * 4 + mi][(nh) * 2 + ni], 0, 0, 0); \
    } \
} while (0)
#define WAITK() do { \
    asm volatile("s_waitcnt lgkmcnt(0)"); \
    __builtin_amdgcn_sched_barrier(0); \
} while (0)
#define KTILE(buf, kt, SP0, SP23, VMC) do { \
    /* P0 */ \
    asm volatile("s_waitcnt vmcnt(" #VMC ")"); \
    __builtin_amdgcn_sched_barrier(0); \
    __builtin_amdgcn_s_barrier(); \
    LD_A(buf, 0); LD_B(buf, 0, bq0); \
    if (SP0) STG_A((buf) ^ 1, 1, (kt) + 1); \
    WAITK(); \
    __builtin_amdgcn_s_setprio(1); MM(0, 0, bq0); __builtin_amdgcn_s_setprio(0); \
    /* P1 */ \
    __builtin_amdgcn_s_barrier(); \
    LD_B(buf, 1, bq1); \
    WAITK(); \
    __builtin_amdgcn_s_setprio(1); MM(0, 1, bq1); __builtin_amdgcn_s_setprio(0); \
    /* P2 */ \
    __builtin_amdgcn_s_barrier(); \
    LD_A(buf, 1); \
    if (SP23) { STG_B(buf, 0, (kt) + 2); STG_B(buf, 1, (kt) + 2); } \
    WAITK(); \
    __builtin_amdgcn_s_setprio(1); MM(1, 1, bq1); __builtin_amdgcn_s_setprio(0); \
    /* P3 */ \
    __builtin_amdgcn_s_barrier(); \
    if (SP23) STG_A(buf, 0, (kt) + 2); \
    __builtin_amdgcn_s_setprio(1); MM(1, 0, bq0); __builtin_amdgcn_s_setprio(0); \
} while (0)

    f32x4 acc[8][4] = {};
    s16x8 af[4][2], bq0[2][2], bq1[2][2];

    // prologue: tile0 (4 halves) + tile1 (B0,B1,A0) = 14 loads in flight.
    // First KTILE's P0 does vmcnt(6) (retires exactly tile0's 8) + barrier.
    STG_B(0, 0, 0); STG_B(0, 1, 0); STG_A(0, 0, 0); STG_A(0, 1, 0);
    STG_B(1, 0, 1); STG_B(1, 1, 1); STG_A(1, 0, 1);

#pragma clang loop unroll(disable)
    for (int it = 0; it < 7; ++it) {    // tiles 0..13: full staging
        int kt = it * 2;
        KTILE(0, kt, 1, 1, 6);
        KTILE(1, kt + 1, 1, 1, 6);
    }
    KTILE(0, 14, 1, 0, 6);              // stages only (15).A1
    KTILE(1, 15, 0, 0, 0);              // drain

#undef KTILE
#undef WAITK
#undef MM
#undef LD_B
#undef LD_A
#undef STG_B
#undef STG_A

    // Epilogue. C/D layout: col = lane&15, row = quad*4 + reg  [verified m89/m91]
#pragma unroll
    for (int ni = 0; ni < 4; ++ni) {
        int gn = n0 + wn * 64 + ni * 16 + l16;
        float bi = bias[t * NSIZE + gn];
#pragma unroll
        for (int mi = 0; mi < 8; ++mi) {
#pragma unroll
            for (int r = 0; r < 4; ++r) {
                int gm = m0 + wm * 128 + mi * 16 + quad * 4 + r;
                size_t o = (size_t)(gm * T_SZ + t) * NSIZE + gn;
                float v = acc[mi][ni][r] + bi;
                if (EPI == 0) {
                    out_bf[o] = f2bf(v);
                } else {
                    out_f[o] = v + resid[o];
                }
            }
        }
    }
}

// ---------------- cross-task attention: 16 lanes per (b,h), 8 dims/lane ----------------
// qkv: bf16 [B][T][3C]; ctx: bf16 [B][T][C]
// All loads/stores are 16 B/lane dwordx4 (round-2 version was 4 B/lane scalar pairs).
// Dim-reduction via 4x shfl_xor within the 16-lane group (xor of lane bits 0..3).
__global__ __launch_bounds__(256) void attn_kernel(const unsigned short* __restrict__ qkv,
                                                   unsigned short* __restrict__ ctx) {
    const int tid = threadIdx.x;
    const int li  = tid & 15;                    // dim-group lane
    const int g   = blockIdx.x * 16 + (tid >> 4);   // [0, B*H)
    const int b   = g >> 3, h = g & 7;
    const int d0  = li * 8;

    const unsigned short* base = qkv + (size_t)b * (T_SZ * NQKV) + h * DH_SZ + d0;
    float qf[4][8], kf[4][8], vf[4][8];
#pragma unroll
    for (int i = 0; i < 4; i++) {
        const unsigned short* p = base + (size_t)i * NQKV;
        s16x8 qv = *reinterpret_cast<const s16x8*>(p);
        s16x8 kv = *reinterpret_cast<const s16x8*>(p + C_SZ);
        s16x8 vv = *reinterpret_cast<const s16x8*>(p + 2 * C_SZ);
#pragma unroll
        for (int e = 0; e < 8; e++) {
            qf[i][e] = bf2f((unsigned short)qv[e]);
            kf[i][e] = bf2f((unsigned short)kv[e]);
            vf[i][e] = bf2f((unsigned short)vv[e]);
        }
    }
    float s[4][4];
#pragma unroll
    for (int i = 0; i < 4; i++)
#pragma unroll
        for (int j = 0; j < 4; j++) {
            float p = 0.0f;
#pragma unroll
            for (int e = 0; e < 8; e++) p += qf[i][e] * kf[j][e];
            p += __shfl_xor(p, 8);
            p += __shfl_xor(p, 4);
            p += __shfl_xor(p, 2);
            p += __shfl_xor(p, 1);
            s[i][j] = p * SCALE_F;
        }
#pragma unroll
    for (int i = 0; i < 4; i++) {
        float m = fmaxf(fmaxf(s[i][0], s[i][1]), fmaxf(s[i][2], s[i][3]));
        float e0 = __expf(s[i][0] - m), e1 = __expf(s[i][1] - m);
        float e2 = __expf(s[i][2] - m), e3 = __expf(s[i][3] - m);
        float inv = 1.0f / (e0 + e1 + e2 + e3);
        s[i][0] = e0 * inv; s[i][1] = e1 * inv; s[i][2] = e2 * inv; s[i][3] = e3 * inv;
    }
#pragma unroll
    for (int i = 0; i < 4; i++) {
        s16x8 ov;
#pragma unroll
        for (int e = 0; e < 8; e++) {
            float o = s[i][0] * vf[0][e] + s[i][1] * vf[1][e]
                    + s[i][2] * vf[2][e] + s[i][3] * vf[3][e];
            ov[e] = (short)f2bf(o);
        }
        *reinterpret_cast<s16x8*>(ctx + (size_t)(b * T_SZ + i) * C_SZ + h * DH_SZ + d0) = ov;
    }
}

// ---------------- LayerNorm over C, one block per (b,t) row ----------------
__global__ __launch_bounds__(256) void ln_kernel(const float* __restrict__ y,
                                                 const float* __restrict__ gamma,
                                                 const float* __restrict__ beta,
                                                 float* __restrict__ out) {
    int row = blockIdx.x;
    int lane = threadIdx.x & 63, wave = threadIdx.x >> 6;
    float4 v = reinterpret_cast<const float4*>(y + (size_t)row * C_SZ)[threadIdx.x];
    float s  = v.x + v.y + v.z + v.w;
    float ss = v.x * v.x + v.y * v.y + v.z * v.z + v.w * v.w;
#pragma unroll
    for (int off = 32; off > 0; off >>= 1) { s += __shfl_xor(s, off); ss += __shfl_xor(ss, off); }
    __shared__ float red[8];
    if (lane == 0) { red[wave] = s; red[wave + 4] = ss; }
    __syncthreads();
    float S  = red[0] + red[1] + red[2] + red[3];
    float SS = red[4] + red[5] + red[6] + red[7];
    float mean = S * (1.0f / C_SZ);
    float var  = SS * (1.0f / C_SZ) - mean * mean;
    float inv  = rsqrtf(var + 1e-5f);
    float4 g  = reinterpret_cast<const float4*>(gamma)[threadIdx.x];
    float4 be = reinterpret_cast<const float4*>(beta)[threadIdx.x];
    float4 o;
    o.x = (v.x - mean) * inv * g.x + be.x;
    o.y = (v.y - mean) * inv * g.y + be.y;
    o.z = (v.z - mean) * inv * g.z + be.z;
    o.w = (v.w - mean) * inv * g.w + be.w;
    reinterpret_cast<float4*>(out + (size_t)row * C_SZ)[threadIdx.x] = o;
}

extern "C" void kernel_launch(void* const* d_in, const int* in_sizes, int n_in,
                              void* d_out, int out_size, void* d_ws, size_t ws_size,
                              hipStream_t stream) {
    const float* feats = (const float*)d_in[0];   // [B,T,C]
    const float* Wqkv  = (const float*)d_in[1];   // [T,C,3C]
    const float* bqkv  = (const float*)d_in[2];   // [T,3C]
    const float* Wproj = (const float*)d_in[3];   // [T,C,C]
    const float* bproj = (const float*)d_in[4];   // [T,C]
    const float* gamma = (const float*)d_in[5];   // [C]
    const float* beta  = (const float*)d_in[6];   // [C]
    float* out = (float*)d_out;

    // ws layout (bytes):
    //   [0,   33.5M)  feats_bf16  [B,T,C]
    //   [33.5M, 58.7M) WqkvT bf16 [T,3C,C]
    //   [58.7M, 67.1M) WprojT bf16 [T,C,C]
    //   [67.1M, 167.8M) qkv bf16 [B,T,3C]   (later aliased by y fp32 [B,T,C] = 67.1MB)
    //   [167.8M, 201.3M) ctx bf16 [B,T,C]
    char* ws = (char*)d_ws;
    unsigned short* feats_bf = (unsigned short*)(ws);
    unsigned short* wqkv_t   = (unsigned short*)(ws + 33554432);
    unsigned short* wproj_t  = (unsigned short*)(ws + 58720256);
    unsigned short* qkv      = (unsigned short*)(ws + 67108864);
    unsigned short* ctx      = (unsigned short*)(ws + 167772160);
    float* ybuf              = (float*)(ws + 67108864);   // aliases qkv (dead after attn)

    cvt_f32_bf16<<<16384, 256, 0, stream>>>(feats, feats_bf, (B_SZ * T_SZ * C_SZ) / 4);
    transpose_cvt<<<dim3(96, 32, 4), dim3(32, 8), 0, stream>>>(Wqkv, wqkv_t, C_SZ, NQKV);
    transpose_cvt<<<dim3(32, 32, 4), dim3(32, 8), 0, stream>>>(Wproj, wproj_t, C_SZ, C_SZ);

    // QKV: grid = (3072/256)*(4096/256)*4 = 768 blocks of 512
    gemm256<NQKV, 0><<<dim3(768), 512, 0, stream>>>(
        feats_bf, wqkv_t, bqkv, nullptr, qkv, nullptr);

    attn_kernel<<<(B_SZ * H_SZ) / 16, 256, 0, stream>>>(qkv, ctx);

    // proj: grid = (1024/256)*(4096/256)*4 = 256 blocks of 512 (exactly 1/CU)
    gemm256<C_SZ, 1><<<dim3(256), 512, 0, stream>>>(
        ctx, wproj_t, bproj, feats, nullptr, ybuf);

    ln_kernel<<<B_SZ * T_SZ, 256, 0, stream>>>(ybuf, gamma, beta, out);
}